// Round 2
// baseline (2325.534 us; speedup 1.0000x reference)
//
#include <hip/hip_runtime.h>

#define BINS 1024
#define DIM  128
#define NTHREADS 256

// Kernel 1: per-row nearest codebook entry (fp32, mirrors reference expression).
// Each thread owns one row held ENTIRELY in VGPRs; embed[b][k] addresses are
// wave-uniform -> scalar (SGPR) loads, FMA takes the SGPR operand directly.
// __launch_bounds__(256, 2): cap 256 VGPR/wave so the 128-float row cannot
// spill (round-1 spilled at 84 VGPRs -> scratch-bound, VALUBusy 22%).
__global__ __launch_bounds__(NTHREADS, 2) void vq_dist_argmax(
    const float* __restrict__ x,
    const float* __restrict__ embed,
    float* __restrict__ ind_f)           // [N] indices as float (d_out tail)
{
    __shared__ float esq_s[BINS];
    // Per-block e_sq (1024 sums of 128 squares) — 0.4% of total FMAs.
    for (int b = threadIdx.x; b < BINS; b += NTHREADS) {
        const float* e = embed + b * DIM;
        float s = 0.f;
        #pragma unroll
        for (int k = 0; k < DIM; ++k) s = fmaf(e[k], e[k], s);
        esq_s[b] = s;
    }
    __syncthreads();

    const int row = blockIdx.x * NTHREADS + threadIdx.x;

    // This thread's row in registers (32 x float4 = 128 VGPRs).
    float xr[DIM];
    {
        const float4* xv = reinterpret_cast<const float4*>(x + (size_t)row * DIM);
        #pragma unroll
        for (int k = 0; k < DIM / 4; ++k) {
            float4 v = xv[k];
            xr[4*k+0] = v.x; xr[4*k+1] = v.y; xr[4*k+2] = v.z; xr[4*k+3] = v.w;
        }
    }

    float xsq = 0.f;
    #pragma unroll
    for (int k = 0; k < DIM; ++k) xsq = fmaf(xr[k], xr[k], xsq);

    float best  = -3.402823466e38f;
    int   bestb = 0;
    // unroll 2: expose next bin's scalar loads while current bin's FMAs issue.
    #pragma unroll 2
    for (int b = 0; b < BINS; ++b) {
        const float* __restrict__ e = embed + b * DIM;  // wave-uniform address
        float a0 = 0.f, a1 = 0.f, a2 = 0.f, a3 = 0.f;   // 4 independent chains
        #pragma unroll
        for (int k = 0; k < DIM; k += 4) {
            a0 = fmaf(xr[k+0], e[k+0], a0);
            a1 = fmaf(xr[k+1], e[k+1], a1);
            a2 = fmaf(xr[k+2], e[k+2], a2);
            a3 = fmaf(xr[k+3], e[k+3], a3);
        }
        float dot = (a0 + a1) + (a2 + a3);
        // Mirror reference: dist = -((x_sq - 2*dot) + e_sq).
        float d = -(fmaf(-2.f, dot, xsq) + esq_s[b]);
        if (d > best) { best = d; bestb = b; }   // strict > == first-wins (jnp.argmax)
    }
    ind_f[row] = (float)bestb;
}

// Kernel 2: quantize = embed[ind], fully coalesced float4 writes.
__global__ __launch_bounds__(256) void vq_gather(
    const float* __restrict__ embed,
    const float* __restrict__ ind_f,
    float4* __restrict__ out)            // N*DIM/4 float4
{
    int i   = blockIdx.x * 256 + threadIdx.x;   // over N*DIM/4
    int row = i >> 5;                           // DIM/4 == 32
    int k   = i & 31;
    int b   = (int)ind_f[row];
    out[i] = reinterpret_cast<const float4*>(embed)[b * (DIM / 4) + k];
}

extern "C" void kernel_launch(void* const* d_in, const int* in_sizes, int n_in,
                              void* d_out, int out_size, void* d_ws, size_t ws_size,
                              hipStream_t stream) {
    const float* x     = (const float*)d_in[0];   // [B*T, 128] fp32
    const float* embed = (const float*)d_in[1];   // [1024, 128] fp32
    float* out = (float*)d_out;

    const int N = in_sizes[0] / DIM;              // 262144
    float* ind_f = out + (size_t)N * DIM;         // output 1 region (indices as float)

    vq_dist_argmax<<<N / NTHREADS, NTHREADS, 0, stream>>>(x, embed, ind_f);

    const int total4 = N * (DIM / 4);             // 8388608 float4 elements
    vq_gather<<<total4 / 256, 256, 0, stream>>>(embed, ind_f, (float4*)out);
}

// Round 3
// 1135.829 us; speedup vs baseline: 2.0474x; 2.0474x over previous
//
#include <hip/hip_runtime.h>

#define DIM   128
#define BINS  1024
#define NT    256
#define ROWS  64          // rows per block
#define TB    128         // bins per tile
#define KS    32          // k per slab
#define NSLAB (DIM/KS)    // 4
#define NTILE (BINS/TB)   // 8
#define NM    (NTILE*NSLAB) // 32 slab-steps
#define XST   132         // xs row stride (floats): +4 pad -> tr groups 2-way
#define EST   36          // es row stride (floats): +4 pad -> lanes spread 4 banks apart

// ---- pre-kernel: esq[b] = sum_k embed[b][k]^2 (same fmaf chain as round 1) ----
__global__ __launch_bounds__(256) void esq_kernel(const float* __restrict__ embed,
                                                  float* __restrict__ esq) {
    int b = blockIdx.x * 256 + threadIdx.x;
    const float* e = embed + (size_t)b * DIM;
    float s = 0.f;
    #pragma unroll
    for (int k = 0; k < DIM; ++k) s = fmaf(e[k], e[k], s);
    esq[b] = s;
}

// ---- main kernel: register-tiled dist + fused argmax ----
// 256 threads as 16 row-groups (tr) x 16 bin-cols (tc).
// Thread tile: 4 rows x 8 bins (bins = tile_base + tc + 16j, ascending in j).
__global__ __launch_bounds__(NT, 2) void vq_dist(
    const float* __restrict__ x,
    const float* __restrict__ embed,
    const float* __restrict__ esq_g,
    float* __restrict__ ind_f)
{
    __shared__ float xs[ROWS * XST];        // 33.8 KB
    __shared__ float es[2][TB * EST];       // 36.9 KB
    __shared__ float red_d[ROWS * 16];      // 4 KB
    __shared__ int   red_b[ROWS * 16];      // 4 KB

    const int tid = threadIdx.x;
    const int tc  = tid & 15;
    const int tr  = tid >> 4;
    const size_t rowbase = (size_t)blockIdx.x * ROWS;

    // stage x tile: 64 rows x 128 floats = 2048 float4, coalesced
    {
        const float4* xg = (const float4*)(x + rowbase * DIM);
        #pragma unroll
        for (int i = 0; i < 8; ++i) {
            int idx4 = tid + NT * i;            // 0..2047
            int r    = idx4 >> 5;               // /32 float4 per row
            int c4   = idx4 & 31;
            float4 v = xg[idx4];
            *(float4*)&xs[r * XST + c4 * 4] = v;
        }
    }
    __syncthreads();

    // per-thread xsq for its 4 rows (redundant across tc, negligible)
    float xsq[4];
    #pragma unroll
    for (int i = 0; i < 4; ++i) {
        const float* xr = &xs[(tr * 4 + i) * XST];
        float s = 0.f;
        #pragma unroll
        for (int q = 0; q < DIM / 4; ++q) {
            float4 v = *(const float4*)&xr[q * 4];
            s = fmaf(v.x, v.x, s); s = fmaf(v.y, v.y, s);
            s = fmaf(v.z, v.z, s); s = fmaf(v.w, v.w, s);
        }
        xsq[i] = s;
    }

    float bestd[4]; int bestb[4];
    #pragma unroll
    for (int i = 0; i < 4; ++i) { bestd[i] = -3.402823466e38f; bestb[i] = 0; }

    // embed slab staging: slab m -> tile t=m>>2, k-slab s=m&3; 128 bins x 32 k
    float4 pf[4];
#define ISSUE(m_) do {                                                        \
        int t_ = (m_) >> 2, s_ = (m_) & 3;                                    \
        const float* eg_ = embed + (size_t)(t_ * TB) * DIM + s_ * KS;         \
        _Pragma("unroll")                                                     \
        for (int i_ = 0; i_ < 4; ++i_) {                                      \
            int idx4_ = tid + NT * i_;       /* 0..1023 */                    \
            int b_    = idx4_ >> 3;          /* bin in tile */                \
            int c4_   = idx4_ & 7;                                            \
            pf[i_] = *(const float4*)(eg_ + (size_t)b_ * DIM + c4_ * 4);      \
        }                                                                     \
    } while (0)
#define WRITE(buf_) do {                                                      \
        _Pragma("unroll")                                                     \
        for (int i_ = 0; i_ < 4; ++i_) {                                      \
            int idx4_ = tid + NT * i_;                                        \
            int b_    = idx4_ >> 3;                                           \
            int c4_   = idx4_ & 7;                                            \
            *(float4*)&es[buf_][b_ * EST + c4_ * 4] = pf[i_];                 \
        }                                                                     \
    } while (0)

    ISSUE(0);
    WRITE(0);
    __syncthreads();

    float acc[4][8];
    for (int m = 0; m < NM; ++m) {
        const int t = m >> 2, s = m & 3, buf = m & 1;
        if (s == 0) {
            #pragma unroll
            for (int i = 0; i < 4; ++i)
                #pragma unroll
                for (int j = 0; j < 8; ++j) acc[i][j] = 0.f;
        }
        if (m < NM - 1) ISSUE(m + 1);   // prefetch next slab into regs

        #pragma unroll
        for (int q = 0; q < KS / 4; ++q) {
            float4 xf[4]; float4 ef[8];
            #pragma unroll
            for (int i = 0; i < 4; ++i)
                xf[i] = *(const float4*)&xs[(tr * 4 + i) * XST + (s * KS + q * 4)];
            #pragma unroll
            for (int j = 0; j < 8; ++j)
                ef[j] = *(const float4*)&es[buf][(tc + 16 * j) * EST + q * 4];
            #pragma unroll
            for (int i = 0; i < 4; ++i)
                #pragma unroll
                for (int j = 0; j < 8; ++j) {
                    acc[i][j] = fmaf(xf[i].x, ef[j].x, acc[i][j]);
                    acc[i][j] = fmaf(xf[i].y, ef[j].y, acc[i][j]);
                    acc[i][j] = fmaf(xf[i].z, ef[j].z, acc[i][j]);
                    acc[i][j] = fmaf(xf[i].w, ef[j].w, acc[i][j]);
                }
        }

        if (s == 3) {  // tile done: fold into running argmax (bin-ascending in j)
            const int tb = t * TB;
            #pragma unroll
            for (int j = 0; j < 8; ++j) {
                const int b = tb + tc + 16 * j;
                const float eq = esq_g[b];
                #pragma unroll
                for (int i = 0; i < 4; ++i) {
                    // same expression as round 1: d = -((xsq - 2*dot) + esq)
                    float d = -(fmaf(-2.f, acc[i][j], xsq[i]) + eq);
                    if (d > bestd[i]) { bestd[i] = d; bestb[i] = b; }
                }
            }
        }

        if (m < NM - 1) {
            __syncthreads();        // everyone done reading es[(m+1)&1] (read at m-1)
            WRITE((m + 1) & 1);
            __syncthreads();
        }
    }

    // final cross-column reduce (16 partials per row), explicit first-wins tie-break
    #pragma unroll
    for (int i = 0; i < 4; ++i) {
        red_d[(tr * 4 + i) * 16 + tc] = bestd[i];
        red_b[(tr * 4 + i) * 16 + tc] = bestb[i];
    }
    __syncthreads();
    if (tid < ROWS) {
        float bd = red_d[tid * 16]; int bb = red_b[tid * 16];
        #pragma unroll
        for (int c = 1; c < 16; ++c) {
            float d = red_d[tid * 16 + c]; int b = red_b[tid * 16 + c];
            if (d > bd || (d == bd && b < bb)) { bd = d; bb = b; }
        }
        ind_f[rowbase + tid] = (float)bb;
    }
#undef ISSUE
#undef WRITE
}

// ---- gather: quantize = embed[ind], coalesced float4 ----
__global__ __launch_bounds__(256) void vq_gather(
    const float* __restrict__ embed,
    const float* __restrict__ ind_f,
    float4* __restrict__ out)
{
    int i   = blockIdx.x * 256 + threadIdx.x;   // over N*DIM/4
    int row = i >> 5;                           // DIM/4 == 32
    int k   = i & 31;
    int b   = (int)ind_f[row];
    out[i] = reinterpret_cast<const float4*>(embed)[b * (DIM / 4) + k];
}

extern "C" void kernel_launch(void* const* d_in, const int* in_sizes, int n_in,
                              void* d_out, int out_size, void* d_ws, size_t ws_size,
                              hipStream_t stream) {
    const float* x     = (const float*)d_in[0];   // [N, 128] fp32
    const float* embed = (const float*)d_in[1];   // [1024, 128] fp32
    float* out = (float*)d_out;

    const int N = in_sizes[0] / DIM;              // 262144
    float* ind_f = out + (size_t)N * DIM;         // output 1 region (indices as float)
    float* esq_g = (float*)d_ws;                  // 4 KB scratch

    esq_kernel<<<BINS / 256, 256, 0, stream>>>(embed, esq_g);
    vq_dist<<<N / ROWS, NT, 0, stream>>>(x, embed, esq_g, ind_f);

    const int total4 = N * (DIM / 4);
    vq_gather<<<total4 / 256, 256, 0, stream>>>(embed, ind_f, (float4*)out);
}

// Round 4
// 305.441 us; speedup vs baseline: 7.6137x; 3.7187x over previous
//
#include <hip/hip_runtime.h>

#define DIM  128
#define BINS 1024

typedef __attribute__((ext_vector_type(8))) short bf16x8;
typedef __attribute__((ext_vector_type(4))) float f32x4;

#define MFMA(a, b, c) __builtin_amdgcn_mfma_f32_16x16x32_bf16(a, b, c, 0, 0, 0)

#define GLDS(gp, lp) __builtin_amdgcn_global_load_lds(                        \
    (const __attribute__((address_space(1))) void*)(gp),                     \
    (__attribute__((address_space(3))) void*)(lp), 16, 0, 0)

// round-to-nearest-even fp32 -> bf16 bits (no NaN/Inf in this data)
__device__ __forceinline__ unsigned short rne16(float f) {
    unsigned u = __float_as_uint(f);
    unsigned r = u + 0x7FFFu + ((u >> 16) & 1u);
    return (unsigned short)(r >> 16);
}

// branchless top-2 insert, strict > (first-wins with ascending bin order)
__device__ __forceinline__ void ins2(float d, int b,
                                     float& d0, int& b0, float& d1, int& b1) {
    bool c1 = d > d1;
    float nd1 = c1 ? d : d1; int nb1 = c1 ? b : b1;
    bool c0 = nd1 > d0;
    d1 = c0 ? d0 : nd1;  b1 = c0 ? b0 : nb1;
    d0 = c0 ? nd1 : d0;  b0 = c0 ? nb1 : b0;
}

// ---- prep: esq (round-1 1-chain fmaf) + E -> swizzled bf16 hi/lo tables ----
__global__ __launch_bounds__(256) void vq_prep(
    const float* __restrict__ embed, unsigned short* __restrict__ ehs,
    unsigned short* __restrict__ els, float* __restrict__ esq_g)
{
    int b = blockIdx.x * 256 + threadIdx.x;  // grid exactly BINS/256
    const float* e = embed + (size_t)b * DIM;
    float s = 0.f;
    #pragma unroll
    for (int k = 0; k < DIM; ++k) s = fmaf(e[k], e[k], s);
    esq_g[b] = s;
    #pragma unroll
    for (int c = 0; c < 16; ++c) {          // 16B chunks of the bf16 row
        int slot = c ^ (b & 7);             // XOR-swizzle baked into storage
        #pragma unroll
        for (int j = 0; j < 8; ++j) {
            float f = e[c * 8 + j];
            unsigned short hb = rne16(f);
            float hf = __uint_as_float((unsigned)hb << 16);
            unsigned short lb = rne16(f - hf);
            ehs[b * 128 + slot * 8 + j] = hb;
            els[b * 128 + slot * 8 + j] = lb;
        }
    }
}

// ---- stage A: MFMA approx distances + per-row top-2 candidates ----
// Block: 512 thr = 8 waves; wave w owns rows base+w*32..+31 (two 16-row sets).
// Swapped GEMM: A = E (16 bins x 32 k), B = X^T (32 k x 16 rows).
// D layout (verified): col(lane&15) = x-row, row((lane>>4)*4+reg) = bin.
__global__ __launch_bounds__(512, 2) void vq_stage_a(
    const float* __restrict__ x,
    const unsigned short* __restrict__ ehs_g,
    const unsigned short* __restrict__ els_g,
    const float* __restrict__ esq_g,
    float* __restrict__ cand)               // [N][2] candidate bins (as float)
{
    __shared__ unsigned short ehb[2][8192];  // 2 x 16 KB (64 bins x 128 bf16)
    __shared__ unsigned short elb[2][8192];
    __shared__ float esq_lds[BINS];

    const int tid = threadIdx.x;
    const int li  = tid & 15;        // x-row within 16-row set / bin-in-tile base
    const int g   = (tid >> 4) & 3;  // k-chunk group
    const int w   = tid >> 6;        // wave id
    const int e7  = li & 7;

    // ---- load + convert this lane's X chunks (rows li, li+16 of wave tile) ----
    bf16x8 xh[2][4], xl[2][4];
    const size_t rowA = (size_t)blockIdx.x * 256 + w * 32 + li;
    #pragma unroll
    for (int rs = 0; rs < 2; ++rs) {
        const float* xp = x + (rowA + rs * 16) * DIM + g * 8;
        #pragma unroll
        for (int s = 0; s < 4; ++s) {
            float4 v0 = *(const float4*)(xp + s * 32);
            float4 v1 = *(const float4*)(xp + s * 32 + 4);
            float f[8] = {v0.x, v0.y, v0.z, v0.w, v1.x, v1.y, v1.z, v1.w};
            bf16x8 h, lo;
            #pragma unroll
            for (int j = 0; j < 8; ++j) {
                unsigned short hb = rne16(f[j]);
                h[j] = (short)hb;
                float hf = __uint_as_float((unsigned)hb << 16);
                lo[j] = (short)rne16(f[j] - hf);
            }
            xh[rs][s] = h; xl[rs][s] = lo;
        }
    }

    // ---- prologue: stage step 0 + esq ----
    {
        const char* gE = (const char*)ehs_g;
        const char* gL = (const char*)els_g;
        char* lE = (char*)&ehb[0][0];
        char* lL = (char*)&elb[0][0];
        int o0 = tid * 16, o1 = tid * 16 + 8192;
        GLDS(gE + o0, lE + o0); GLDS(gE + o1, lE + o1);
        GLDS(gL + o0, lL + o0); GLDS(gL + o1, lL + o1);
    }
    esq_lds[tid] = esq_g[tid];
    esq_lds[tid + 512] = esq_g[tid + 512];
    asm volatile("s_waitcnt vmcnt(0)" ::: "memory");
    __syncthreads();

    float dA0 = -3.402823466e38f, dA1 = -3.402823466e38f;
    float dB0 = -3.402823466e38f, dB1 = -3.402823466e38f;
    int bA0 = 0, bA1 = 0, bB0 = 0, bB1 = 0;

    for (int stp = 0; stp < 16; ++stp) {     // 16 steps x 64 bins
        const int buf = stp & 1;
        if (stp < 15) {                       // prefetch next chunk
            const char* gE = (const char*)ehs_g + (size_t)(stp + 1) * 16384;
            const char* gL = (const char*)els_g + (size_t)(stp + 1) * 16384;
            char* lE = (char*)&ehb[buf ^ 1][0];
            char* lL = (char*)&elb[buf ^ 1][0];
            int o0 = tid * 16, o1 = tid * 16 + 8192;
            GLDS(gE + o0, lE + o0); GLDS(gE + o1, lE + o1);
            GLDS(gL + o0, lL + o0); GLDS(gL + o1, lL + o1);
        }
        const char* bE = (const char*)&ehb[buf][0];
        const char* bL = (const char*)&elb[buf][0];
        #pragma unroll
        for (int tl = 0; tl < 4; ++tl) {      // 4 bin-tiles of 16
            f32x4 aP0 = {0.f,0.f,0.f,0.f}, aP1 = {0.f,0.f,0.f,0.f};
            f32x4 aQ0 = {0.f,0.f,0.f,0.f}, aQ1 = {0.f,0.f,0.f,0.f};
            #pragma unroll
            for (int s = 0; s < 4; ++s) {     // K = 128 in 4 x 32
                int sb = tl * 4096 + li * 256 + (((g + 4 * s) ^ e7) << 4);
                bf16x8 eh = *(const bf16x8*)(bE + sb);
                bf16x8 el = *(const bf16x8*)(bL + sb);
                aP0 = MFMA(eh, xh[0][s], aP0);
                aP1 = MFMA(eh, xh[1][s], aP1);
                aQ0 = MFMA(el, xh[0][s], aQ0);
                aQ1 = MFMA(el, xh[1][s], aQ1);
                aQ0 = MFMA(eh, xl[0][s], aQ0);
                aQ1 = MFMA(eh, xl[1][s], aQ1);
            }
            // fold into top-2; key = 2*dot - esq (monotone in -dist, xsq common)
            const int binb = stp * 64 + tl * 16 + g * 4;
            const f32x4 eq = *(const f32x4*)&esq_lds[binb];
            #pragma unroll
            for (int r = 0; r < 4; ++r) {
                float kA = fmaf(2.f, aP0[r] + aQ0[r], -eq[r]);
                ins2(kA, binb + r, dA0, bA0, dA1, bA1);
                float kB = fmaf(2.f, aP1[r] + aQ1[r], -eq[r]);
                ins2(kB, binb + r, dB0, bB0, dB1, bB1);
            }
        }
        asm volatile("s_waitcnt vmcnt(0)" ::: "memory");
        __syncthreads();
    }

    // ---- merge the 4 k-groups (disjoint bin sets, same rows) ----
    #pragma unroll
    for (int mm = 16; mm <= 32; mm <<= 1) {
        float pd0 = __shfl_xor(dA0, mm); int pb0 = __shfl_xor(bA0, mm);
        float pd1 = __shfl_xor(dA1, mm); int pb1 = __shfl_xor(bA1, mm);
        ins2(pd0, pb0, dA0, bA0, dA1, bA1);
        ins2(pd1, pb1, dA0, bA0, dA1, bA1);
        pd0 = __shfl_xor(dB0, mm); pb0 = __shfl_xor(bB0, mm);
        pd1 = __shfl_xor(dB1, mm); pb1 = __shfl_xor(bB1, mm);
        ins2(pd0, pb0, dB0, bB0, dB1, bB1);
        ins2(pd1, pb1, dB0, bB0, dB1, bB1);
    }
    if ((tid & 63) < 16) {
        cand[rowA * 2 + 0] = (float)bA0;
        cand[rowA * 2 + 1] = (float)bA1;
        cand[(rowA + 16) * 2 + 0] = (float)bB0;
        cand[(rowA + 16) * 2 + 1] = (float)bB1;
    }
}

// ---- rescore: exact fp32 (round-1-proven expression) on 2 candidates ----
__global__ __launch_bounds__(256) void vq_rescore(
    const float* __restrict__ x, const float* __restrict__ embed,
    const float* __restrict__ esq_g, const float* __restrict__ cand,
    float* __restrict__ ind_f)
{
    __shared__ float xsm[256 * 129];         // 129-stride: conflict-free rows
    const int tid = threadIdx.x;
    const size_t base = (size_t)blockIdx.x * 256;
    const float4* xg = (const float4*)(x + base * DIM);
    #pragma unroll
    for (int i = 0; i < 32; ++i) {
        int idx = tid + 256 * i;
        int r = idx >> 5, c4 = idx & 31;
        float4 v = xg[idx];
        float* dst = &xsm[r * 129 + c4 * 4];
        dst[0] = v.x; dst[1] = v.y; dst[2] = v.z; dst[3] = v.w;
    }
    __syncthreads();

    const float* xr = &xsm[tid * 129];
    float xsq = 0.f;
    #pragma unroll
    for (int k = 0; k < DIM; ++k) xsq = fmaf(xr[k], xr[k], xsq);

    const size_t row = base + tid;
    int bb[2] = {(int)cand[row * 2], (int)cand[row * 2 + 1]};
    float dd[2];
    #pragma unroll
    for (int c = 0; c < 2; ++c) {
        const float* e = embed + (size_t)bb[c] * DIM;
        float a0 = 0.f, a1 = 0.f, a2 = 0.f, a3 = 0.f;
        #pragma unroll
        for (int k = 0; k < DIM; k += 4) {
            a0 = fmaf(xr[k + 0], e[k + 0], a0);
            a1 = fmaf(xr[k + 1], e[k + 1], a1);
            a2 = fmaf(xr[k + 2], e[k + 2], a2);
            a3 = fmaf(xr[k + 3], e[k + 3], a3);
        }
        float dot = (a0 + a1) + (a2 + a3);
        dd[c] = -(fmaf(-2.f, dot, xsq) + esq_g[bb[c]]);   // round-1 expression
    }
    int wb = bb[0];
    if (dd[1] > dd[0] || (dd[1] == dd[0] && bb[1] < bb[0])) wb = bb[1];
    ind_f[row] = (float)wb;
}

// ---- gather: quantize = embed[ind], coalesced float4 ----
__global__ __launch_bounds__(256) void vq_gather(
    const float* __restrict__ embed,
    const float* __restrict__ ind_f,
    float4* __restrict__ out)
{
    int i   = blockIdx.x * 256 + threadIdx.x;   // over N*DIM/4
    int row = i >> 5;                           // DIM/4 == 32
    int k   = i & 31;
    int b   = (int)ind_f[row];
    out[i] = reinterpret_cast<const float4*>(embed)[b * (DIM / 4) + k];
}

extern "C" void kernel_launch(void* const* d_in, const int* in_sizes, int n_in,
                              void* d_out, int out_size, void* d_ws, size_t ws_size,
                              hipStream_t stream) {
    const float* x     = (const float*)d_in[0];   // [N, 128] fp32
    const float* embed = (const float*)d_in[1];   // [1024, 128] fp32
    float* out = (float*)d_out;

    const int N = in_sizes[0] / DIM;              // 262144
    float* ind_f = out + (size_t)N * DIM;         // output 1 (indices as float)

    // scratch carved out of the quantize region (fully overwritten by gather):
    char* ob = (char*)d_out;
    float* cand = out;                                        // [N][2] floats (2 MB)
    unsigned short* ehs = (unsigned short*)(ob + (32u << 20)); // 256 KB
    unsigned short* els = (unsigned short*)(ob + (34u << 20)); // 256 KB
    float* esq_g        = (float*)(ob + (36u << 20));          // 4 KB

    vq_prep<<<BINS / 256, 256, 0, stream>>>(embed, ehs, els, esq_g);
    vq_stage_a<<<N / 256, 512, 0, stream>>>(x, ehs, els, esq_g, cand);
    vq_rescore<<<N / 256, 256, 0, stream>>>(x, embed, esq_g, cand, ind_f);
    vq_gather<<<(N * (DIM / 4)) / 256, 256, 0, stream>>>(embed, ind_f, (float4*)out);
}

// Round 5
// 289.613 us; speedup vs baseline: 8.0298x; 1.0547x over previous
//
#include <hip/hip_runtime.h>

#define DIM  128
#define BINS 1024

typedef __attribute__((ext_vector_type(8))) short bf16x8;
typedef __attribute__((ext_vector_type(4))) float f32x4;

#define MFMA(a, b, c) __builtin_amdgcn_mfma_f32_16x16x32_bf16(a, b, c, 0, 0, 0)

#define GLDS(gp, lp) __builtin_amdgcn_global_load_lds(                        \
    (const __attribute__((address_space(1))) void*)(gp),                     \
    (__attribute__((address_space(3))) void*)(lp), 16, 0, 0)

// round-to-nearest-even fp32 -> bf16 bits (no NaN/Inf in this data)
__device__ __forceinline__ unsigned short rne16(float f) {
    unsigned u = __float_as_uint(f);
    unsigned r = u + 0x7FFFu + ((u >> 16) & 1u);
    return (unsigned short)(r >> 16);
}

// branchless top-2 insert, strict > (first-wins with ascending bin order)
__device__ __forceinline__ void ins2(float d, int b,
                                     float& d0, int& b0, float& d1, int& b1) {
    bool c1 = d > d1;
    float nd1 = c1 ? d : d1; int nb1 = c1 ? b : b1;
    bool c0 = nd1 > d0;
    d1 = c0 ? d0 : nd1;  b1 = c0 ? b0 : nb1;
    d0 = c0 ? nd1 : d0;  b0 = c0 ? nb1 : b0;
}

// ---- prep: esq (round-1 1-chain fmaf) + E -> swizzled bf16 hi/lo tables ----
// Full 4-bit XOR swizzle (was 3-bit in round 4 -> 2-way alias, 16.8M conflicts)
__global__ __launch_bounds__(256) void vq_prep(
    const float* __restrict__ embed, unsigned short* __restrict__ ehs,
    unsigned short* __restrict__ els, float* __restrict__ esq_g)
{
    int b = blockIdx.x * 256 + threadIdx.x;  // grid exactly BINS/256
    const float* e = embed + (size_t)b * DIM;
    float s = 0.f;
    #pragma unroll
    for (int k = 0; k < DIM; ++k) s = fmaf(e[k], e[k], s);
    esq_g[b] = s;
    #pragma unroll
    for (int c = 0; c < 16; ++c) {          // 16B chunks of the bf16 row
        int slot = c ^ (b & 15);            // XOR-swizzle baked into storage
        #pragma unroll
        for (int j = 0; j < 8; ++j) {
            float f = e[c * 8 + j];
            unsigned short hb = rne16(f);
            float hf = __uint_as_float((unsigned)hb << 16);
            unsigned short lb = rne16(f - hf);
            ehs[b * 128 + slot * 8 + j] = hb;
            els[b * 128 + slot * 8 + j] = lb;
        }
    }
}

// ---- stage A: MFMA approx distances + per-row top-2 candidates ----
// Block: 512 thr = 8 waves; wave w owns rows base+w*32..+31 (two 16-row sets).
// Swapped GEMM: A = E (16 bins x 32 k), B = X^T (32 k x 16 rows).
// D layout (verified): col(lane&15) = x-row, row((lane>>4)*4+reg) = bin.
__global__ __launch_bounds__(512, 2) void vq_stage_a(
    const float* __restrict__ x,
    const unsigned short* __restrict__ ehs_g,
    const unsigned short* __restrict__ els_g,
    const float* __restrict__ esq_g,
    float* __restrict__ cand)               // [N][2] candidate bins (as float)
{
    __shared__ unsigned short ehb[2][8192];  // 2 x 16 KB (64 bins x 128 bf16)
    __shared__ unsigned short elb[2][8192];
    __shared__ float esq_lds[BINS];

    const int tid = threadIdx.x;
    const int li  = tid & 15;        // x-row within 16-row set / bin row in tile
    const int g   = (tid >> 4) & 3;  // k-chunk group
    const int w   = tid >> 6;        // wave id

    // ---- load + convert this lane's X chunks (rows li, li+16 of wave tile) ----
    bf16x8 xh[2][4], xl[2][4];
    const size_t rowA = (size_t)blockIdx.x * 256 + w * 32 + li;
    #pragma unroll
    for (int rs = 0; rs < 2; ++rs) {
        const float* xp = x + (rowA + rs * 16) * DIM + g * 8;
        #pragma unroll
        for (int s = 0; s < 4; ++s) {
            float4 v0 = *(const float4*)(xp + s * 32);
            float4 v1 = *(const float4*)(xp + s * 32 + 4);
            float f[8] = {v0.x, v0.y, v0.z, v0.w, v1.x, v1.y, v1.z, v1.w};
            bf16x8 h, lo;
            #pragma unroll
            for (int j = 0; j < 8; ++j) {
                unsigned short hb = rne16(f[j]);
                h[j] = (short)hb;
                float hf = __uint_as_float((unsigned)hb << 16);
                lo[j] = (short)rne16(f[j] - hf);
            }
            xh[rs][s] = h; xl[rs][s] = lo;
        }
    }

    // ---- prologue: stage step 0 + esq ----
    {
        const char* gE = (const char*)ehs_g;
        const char* gL = (const char*)els_g;
        char* lE = (char*)&ehb[0][0];
        char* lL = (char*)&elb[0][0];
        int o0 = tid * 16, o1 = tid * 16 + 8192;
        GLDS(gE + o0, lE + o0); GLDS(gE + o1, lE + o1);
        GLDS(gL + o0, lL + o0); GLDS(gL + o1, lL + o1);
    }
    esq_lds[tid] = esq_g[tid];
    esq_lds[tid + 512] = esq_g[tid + 512];
    asm volatile("s_waitcnt vmcnt(0)" ::: "memory");
    __syncthreads();

    float dA0 = -3.402823466e38f, dA1 = -3.402823466e38f;
    float dB0 = -3.402823466e38f, dB1 = -3.402823466e38f;
    int bA0 = 0, bA1 = 0, bB0 = 0, bB1 = 0;

    // fragment address: row (tl*16+li) at tl*4096+li*256; chunk (g+4s) at
    // slot ((g+4s)^li)*16  (matches vq_prep's c ^ (b&15) since bin&15 == li)
#define LDE(tl_, s_) (*(const bf16x8*)(bE + (tl_) * 4096 + li * 256 + (((g + 4 * (s_)) ^ li) << 4)))
#define LDL(tl_, s_) (*(const bf16x8*)(bL + (tl_) * 4096 + li * 256 + (((g + 4 * (s_)) ^ li) << 4)))

    for (int stp = 0; stp < 16; ++stp) {     // 16 steps x 64 bins
        const int buf = stp & 1;
        if (stp < 15) {                       // prefetch next chunk into buf^1
            const char* gE = (const char*)ehs_g + (size_t)(stp + 1) * 16384;
            const char* gL = (const char*)els_g + (size_t)(stp + 1) * 16384;
            char* lE = (char*)&ehb[buf ^ 1][0];
            char* lL = (char*)&elb[buf ^ 1][0];
            int o0 = tid * 16, o1 = tid * 16 + 8192;
            GLDS(gE + o0, lE + o0); GLDS(gE + o1, lE + o1);
            GLDS(gL + o0, lL + o0); GLDS(gL + o1, lL + o1);
        }
        const char* bE = (const char*)&ehb[buf][0];
        const char* bL = (const char*)&elb[buf][0];

        // software-pipelined fragment loads: frag (tl,s+1)/(tl+1,0) issued
        // before (tl,s)'s MFMAs; fold window covers the cross-tile load.
        bf16x8 ehc = LDE(0, 0), elc = LDL(0, 0);
        #pragma unroll
        for (int tl = 0; tl < 4; ++tl) {
            f32x4 aP0 = {0.f,0.f,0.f,0.f}, aP1 = {0.f,0.f,0.f,0.f};
            f32x4 aQ0 = {0.f,0.f,0.f,0.f}, aQ1 = {0.f,0.f,0.f,0.f};
            #pragma unroll
            for (int s = 0; s < 4; ++s) {
                bf16x8 ehn = ehc, eln = elc;
                int ns = s + 1, ntl = tl;
                if (ns == 4) { ns = 0; ntl = tl + 1; }
                if (ntl < 4) { ehn = LDE(ntl, ns); eln = LDL(ntl, ns); }
                aP0 = MFMA(ehc, xh[0][s], aP0);
                aP1 = MFMA(ehc, xh[1][s], aP1);
                aQ0 = MFMA(elc, xh[0][s], aQ0);
                aQ1 = MFMA(elc, xh[1][s], aQ1);
                aQ0 = MFMA(ehc, xl[0][s], aQ0);
                aQ1 = MFMA(ehc, xl[1][s], aQ1);
                ehc = ehn; elc = eln;
            }
            // fold into top-2; key = 2*dot - esq (monotone in -dist, xsq common)
            const int binb = stp * 64 + tl * 16 + g * 4;
            const f32x4 eq = *(const f32x4*)&esq_lds[binb];
            #pragma unroll
            for (int r = 0; r < 4; ++r) {
                float kA = fmaf(2.f, aP0[r] + aQ0[r], -eq[r]);
                ins2(kA, binb + r, dA0, bA0, dA1, bA1);
                float kB = fmaf(2.f, aP1[r] + aQ1[r], -eq[r]);
                ins2(kB, binb + r, dB0, bB0, dB1, bB1);
            }
        }
        asm volatile("s_waitcnt vmcnt(0)" ::: "memory");
        __syncthreads();
    }
#undef LDE
#undef LDL

    // ---- merge the 4 k-groups (disjoint bin sets, same rows) ----
    #pragma unroll
    for (int mm = 16; mm <= 32; mm <<= 1) {
        float pd0 = __shfl_xor(dA0, mm); int pb0 = __shfl_xor(bA0, mm);
        float pd1 = __shfl_xor(dA1, mm); int pb1 = __shfl_xor(bA1, mm);
        ins2(pd0, pb0, dA0, bA0, dA1, bA1);
        ins2(pd1, pb1, dA0, bA0, dA1, bA1);
        pd0 = __shfl_xor(dB0, mm); pb0 = __shfl_xor(bB0, mm);
        pd1 = __shfl_xor(dB1, mm); pb1 = __shfl_xor(bB1, mm);
        ins2(pd0, pb0, dB0, bB0, dB1, bB1);
        ins2(pd1, pb1, dB0, bB0, dB1, bB1);
    }
    if ((tid & 63) < 16) {
        cand[rowA * 2 + 0] = (float)bA0;
        cand[rowA * 2 + 1] = (float)bA1;
        cand[(rowA + 16) * 2 + 0] = (float)bB0;
        cand[(rowA + 16) * 2 + 1] = (float)bB1;
    }
}

// ---- rescore: exact fp32 (round-1-proven expression) on 2 candidates ----
__global__ __launch_bounds__(256) void vq_rescore(
    const float* __restrict__ x, const float* __restrict__ embed,
    const float* __restrict__ esq_g, const float* __restrict__ cand,
    float* __restrict__ ind_f)
{
    __shared__ float xsm[256 * 129];         // 129-stride: conflict-free rows
    const int tid = threadIdx.x;
    const size_t base = (size_t)blockIdx.x * 256;
    const float4* xg = (const float4*)(x + base * DIM);
    #pragma unroll
    for (int i = 0; i < 32; ++i) {
        int idx = tid + 256 * i;
        int r = idx >> 5, c4 = idx & 31;
        float4 v = xg[idx];
        float* dst = &xsm[r * 129 + c4 * 4];
        dst[0] = v.x; dst[1] = v.y; dst[2] = v.z; dst[3] = v.w;
    }
    __syncthreads();

    const float* xr = &xsm[tid * 129];
    float xsq = 0.f;
    #pragma unroll
    for (int k = 0; k < DIM; ++k) xsq = fmaf(xr[k], xr[k], xsq);

    const size_t row = base + tid;
    int bb[2] = {(int)cand[row * 2], (int)cand[row * 2 + 1]};
    float dd[2];
    #pragma unroll
    for (int c = 0; c < 2; ++c) {
        const float* e = embed + (size_t)bb[c] * DIM;
        float a0 = 0.f, a1 = 0.f, a2 = 0.f, a3 = 0.f;
        #pragma unroll
        for (int k = 0; k < DIM; k += 4) {
            a0 = fmaf(xr[k + 0], e[k + 0], a0);
            a1 = fmaf(xr[k + 1], e[k + 1], a1);
            a2 = fmaf(xr[k + 2], e[k + 2], a2);
            a3 = fmaf(xr[k + 3], e[k + 3], a3);
        }
        float dot = (a0 + a1) + (a2 + a3);
        dd[c] = -(fmaf(-2.f, dot, xsq) + esq_g[bb[c]]);   // round-1 expression
    }
    int wb = bb[0];
    if (dd[1] > dd[0] || (dd[1] == dd[0] && bb[1] < bb[0])) wb = bb[1];
    ind_f[row] = (float)wb;
}

// ---- gather: quantize = embed[ind], coalesced float4 ----
__global__ __launch_bounds__(256) void vq_gather(
    const float* __restrict__ embed,
    const float* __restrict__ ind_f,
    float4* __restrict__ out)
{
    int i   = blockIdx.x * 256 + threadIdx.x;   // over N*DIM/4
    int row = i >> 5;                           // DIM/4 == 32
    int k   = i & 31;
    int b   = (int)ind_f[row];
    out[i] = reinterpret_cast<const float4*>(embed)[b * (DIM / 4) + k];
}

extern "C" void kernel_launch(void* const* d_in, const int* in_sizes, int n_in,
                              void* d_out, int out_size, void* d_ws, size_t ws_size,
                              hipStream_t stream) {
    const float* x     = (const float*)d_in[0];   // [N, 128] fp32
    const float* embed = (const float*)d_in[1];   // [1024, 128] fp32
    float* out = (float*)d_out;

    const int N = in_sizes[0] / DIM;              // 262144
    float* ind_f = out + (size_t)N * DIM;         // output 1 (indices as float)

    // scratch carved out of the quantize region (fully overwritten by gather):
    char* ob = (char*)d_out;
    float* cand = out;                                        // [N][2] floats (2 MB)
    unsigned short* ehs = (unsigned short*)(ob + (32u << 20)); // 256 KB
    unsigned short* els = (unsigned short*)(ob + (34u << 20)); // 256 KB
    float* esq_g        = (float*)(ob + (36u << 20));          // 4 KB

    vq_prep<<<BINS / 256, 256, 0, stream>>>(embed, ehs, els, esq_g);
    vq_stage_a<<<N / 256, 512, 0, stream>>>(x, ehs, els, esq_g, cand);
    vq_rescore<<<N / 256, 256, 0, stream>>>(x, embed, esq_g, cand, ind_f);
    vq_gather<<<(N * (DIM / 4)) / 256, 256, 0, stream>>>(embed, ind_f, (float4*)out);
}